// Round 1
// baseline (176.002 us; speedup 1.0000x reference)
//
#include <hip/hip_runtime.h>
#include <math.h>

#define TEXD 256

// Phase 1: per (b,p) compute projected grid coords + visibility, scatter into
// grid workspace [B, TEX*TEX, 2] and mask output [B, TEX*TEX].
__global__ void flame_scatter_kernel(const float* __restrict__ tmv,   // [B,V,3]
                                     const float* __restrict__ vn,    // [B,V,3]
                                     const float* __restrict__ cam,   // [B,3]
                                     const int*   __restrict__ faces, // [P,3]
                                     const float* __restrict__ bc,    // [P,3]
                                     const int*   __restrict__ xs,    // [P]
                                     const int*   __restrict__ ys,    // [P]
                                     float* __restrict__ grid,        // [B,TEX*TEX,2]
                                     float* __restrict__ mask_out,    // [B,TEX*TEX]
                                     int B, int P, int V) {
    int idx = blockIdx.x * blockDim.x + threadIdx.x;
    if (idx >= B * P) return;
    int b = idx / P;
    int p = idx - b * P;

    int f0 = faces[p * 3 + 0];
    int f1 = faces[p * 3 + 1];
    int f2 = faces[p * 3 + 2];
    float w0 = bc[p * 3 + 0];
    float w1 = bc[p * 3 + 1];
    float w2 = bc[p * 3 + 2];

    const float* tb = tmv + (size_t)b * V * 3;
    float px = tb[f0 * 3 + 0] * w0 + tb[f1 * 3 + 0] * w1 + tb[f2 * 3 + 0] * w2;
    float py = tb[f0 * 3 + 1] * w0 + tb[f1 * 3 + 1] * w1 + tb[f2 * 3 + 1] * w2;

    float f  = cam[b * 3 + 0];
    float cx = cam[b * 3 + 1];
    float cy = cam[b * 3 + 2];
    float gx = f * (px + cx);
    float gy = -(f * (py + cy));

    const float* nb = vn + (size_t)b * V * 3;
    float nz = nb[f0 * 3 + 2] * w0 + nb[f1 * 3 + 2] * w1 + nb[f2 * 3 + 2] * w2;

    int t = ys[p] * TEXD + xs[p];
    size_t gbase = ((size_t)b * TEXD * TEXD + t) * 2;
    grid[gbase + 0] = gx;
    grid[gbase + 1] = gy;
    mask_out[(size_t)b * TEXD * TEXD + t] = (nz < 0.0f) ? 1.0f : 0.0f;
}

// Phase 2: per (b,texel) bilinear zero-padded grid_sample of source_img,
// 3 channels, align_corners=False.
__global__ void flame_sample_kernel(const float* __restrict__ img,  // [B,3,HW,HW]
                                    const float* __restrict__ grid, // [B,TEX*TEX,2]
                                    float* __restrict__ out,        // [B,3,TEX,TEX]
                                    int B, int HW) {
    int idx = blockIdx.x * blockDim.x + threadIdx.x;
    int total = B * TEXD * TEXD;
    if (idx >= total) return;
    int b = idx / (TEXD * TEXD);
    int t = idx - b * (TEXD * TEXD);

    size_t gbase = ((size_t)b * TEXD * TEXD + t) * 2;
    float gxn = grid[gbase + 0];
    float gyn = grid[gbase + 1];

    float half = 0.5f * (float)HW;
    float gx = (gxn + 1.0f) * half - 0.5f;
    float gy = (gyn + 1.0f) * half - 0.5f;

    float x0f = floorf(gx);
    float y0f = floorf(gy);
    float wx = gx - x0f;
    float wy = gy - y0f;
    int x0 = (int)x0f;
    int y0 = (int)y0f;
    int x1 = x0 + 1;
    int y1 = y0 + 1;

    bool vx0 = (x0 >= 0) && (x0 <= HW - 1);
    bool vx1 = (x1 >= 0) && (x1 <= HW - 1);
    bool vy0 = (y0 >= 0) && (y0 <= HW - 1);
    bool vy1 = (y1 >= 0) && (y1 <= HW - 1);

    int cx0 = min(max(x0, 0), HW - 1);
    int cx1 = min(max(x1, 0), HW - 1);
    int cy0 = min(max(y0, 0), HW - 1);
    int cy1 = min(max(y1, 0), HW - 1);

    float w00 = (1.0f - wx) * (1.0f - wy) * ((vx0 && vy0) ? 1.0f : 0.0f);
    float w01 = wx * (1.0f - wy) * ((vx1 && vy0) ? 1.0f : 0.0f);
    float w10 = (1.0f - wx) * wy * ((vx0 && vy1) ? 1.0f : 0.0f);
    float w11 = wx * wy * ((vx1 && vy1) ? 1.0f : 0.0f);

    size_t r0 = (size_t)cy0 * HW;
    size_t r1 = (size_t)cy1 * HW;

#pragma unroll
    for (int c = 0; c < 3; ++c) {
        const float* base = img + ((size_t)(b * 3 + c) * HW) * HW;
        float v = base[r0 + cx0] * w00 + base[r0 + cx1] * w01 +
                  base[r1 + cx0] * w10 + base[r1 + cx1] * w11;
        out[(size_t)(b * 3 + c) * TEXD * TEXD + t] = v;
    }
}

extern "C" void kernel_launch(void* const* d_in, const int* in_sizes, int n_in,
                              void* d_out, int out_size, void* d_ws, size_t ws_size,
                              hipStream_t stream) {
    const float* source_img = (const float*)d_in[0];
    const float* tmv        = (const float*)d_in[1];
    const float* vn         = (const float*)d_in[2];
    const float* cam        = (const float*)d_in[3];
    const int*   faces      = (const int*)d_in[4];
    const float* bc         = (const float*)d_in[5];
    const int*   xs         = (const int*)d_in[6];
    const int*   ys         = (const int*)d_in[7];

    int B = in_sizes[3] / 3;                       // 16
    int P = in_sizes[4] / 3;                       // 60000
    int V = in_sizes[1] / (3 * B);                 // 5023
    int HW = (int)(sqrt((double)(in_sizes[0] / (3 * B))) + 0.5); // 512

    size_t texels = (size_t)B * TEXD * TEXD;       // 1,048,576

    float* grid = (float*)d_ws;                    // B*TEX*TEX*2 floats = 8 MB
    float* out = (float*)d_out;
    float* mask_out = out + (size_t)B * 3 * TEXD * TEXD;

    // Zero-init grid workspace and mask output region (harness poisons 0xAA).
    hipMemsetAsync(grid, 0, texels * 2 * sizeof(float), stream);
    hipMemsetAsync(mask_out, 0, texels * sizeof(float), stream);

    int nscatter = B * P;
    flame_scatter_kernel<<<(nscatter + 255) / 256, 256, 0, stream>>>(
        tmv, vn, cam, faces, bc, xs, ys, grid, mask_out, B, P, V);

    flame_sample_kernel<<<((int)texels + 255) / 256, 256, 0, stream>>>(
        source_img, grid, out, B, HW);
}

// Round 2
// 158.387 us; speedup vs baseline: 1.1112x; 1.1112x over previous
//
#include <hip/hip_runtime.h>
#include <math.h>

#define TEXD 256

// Phase 1: tiny scatter — build texel -> p map (same for all batches).
__global__ void flame_build_map_kernel(const int* __restrict__ xs, // [P]
                                       const int* __restrict__ ys, // [P]
                                       int* __restrict__ map,      // [TEX*TEX], pre-set to -1
                                       int P) {
    int p = blockIdx.x * blockDim.x + threadIdx.x;
    if (p >= P) return;
    map[ys[p] * TEXD + xs[p]] = p;
}

// Phase 2: fused projection + bilinear grid_sample + visibility mask.
// One thread per (b, texel). blockIdx % B selects batch so that XCD
// (= blockIdx % 8 heuristic) sees only batches {b, b+8}: 6 MB image working
// set per 4 MB L2 instead of all 16 batches (48 MB).
__global__ void flame_fused_kernel(const float* __restrict__ img,   // [B,3,HW,HW]
                                   const float* __restrict__ tmv,   // [B,V,3]
                                   const float* __restrict__ vn,    // [B,V,3]
                                   const float* __restrict__ cam,   // [B,3]
                                   const int*   __restrict__ faces, // [P,3]
                                   const float* __restrict__ bc,    // [P,3]
                                   const int*   __restrict__ map,   // [TEX*TEX]
                                   float* __restrict__ out_img,     // [B,3,TEX,TEX]
                                   float* __restrict__ out_mask,    // [B,TEX,TEX]
                                   int B, int V, int HW) {
    int b = blockIdx.x % B;
    int tile = blockIdx.x / B;
    int t = tile * blockDim.x + threadIdx.x;
    if (t >= TEXD * TEXD) return;

    int p = map[t];

    float gxn = 0.0f, gyn = 0.0f;
    float maskv = 0.0f;

    if (p >= 0) {
        int f0 = faces[p * 3 + 0];
        int f1 = faces[p * 3 + 1];
        int f2 = faces[p * 3 + 2];
        float w0 = bc[p * 3 + 0];
        float w1 = bc[p * 3 + 1];
        float w2 = bc[p * 3 + 2];

        const float* tb = tmv + (size_t)b * V * 3;
        float px = tb[f0 * 3 + 0] * w0 + tb[f1 * 3 + 0] * w1 + tb[f2 * 3 + 0] * w2;
        float py = tb[f0 * 3 + 1] * w0 + tb[f1 * 3 + 1] * w1 + tb[f2 * 3 + 1] * w2;

        const float* nb = vn + (size_t)b * V * 3;
        float nz = nb[f0 * 3 + 2] * w0 + nb[f1 * 3 + 2] * w1 + nb[f2 * 3 + 2] * w2;

        float fo = cam[b * 3 + 0];
        float cx = cam[b * 3 + 1];
        float cy = cam[b * 3 + 2];
        gxn = fo * (px + cx);
        gyn = -(fo * (py + cy));
        maskv = (nz < 0.0f) ? 1.0f : 0.0f;
    }

    // --- bilinear grid_sample, zero padding, align_corners=False ---
    float half = 0.5f * (float)HW;
    float gx = (gxn + 1.0f) * half - 0.5f;
    float gy = (gyn + 1.0f) * half - 0.5f;

    float x0f = floorf(gx);
    float y0f = floorf(gy);
    float wx = gx - x0f;
    float wy = gy - y0f;
    int x0 = (int)x0f;
    int y0 = (int)y0f;
    int x1 = x0 + 1;
    int y1 = y0 + 1;

    bool vx0 = (x0 >= 0) && (x0 <= HW - 1);
    bool vx1 = (x1 >= 0) && (x1 <= HW - 1);
    bool vy0 = (y0 >= 0) && (y0 <= HW - 1);
    bool vy1 = (y1 >= 0) && (y1 <= HW - 1);

    int cx0 = min(max(x0, 0), HW - 1);
    int cx1 = min(max(x1, 0), HW - 1);
    int cy0 = min(max(y0, 0), HW - 1);
    int cy1 = min(max(y1, 0), HW - 1);

    float w00 = (1.0f - wx) * (1.0f - wy) * ((vx0 && vy0) ? 1.0f : 0.0f);
    float w01 = wx * (1.0f - wy) * ((vx1 && vy0) ? 1.0f : 0.0f);
    float w10 = (1.0f - wx) * wy * ((vx0 && vy1) ? 1.0f : 0.0f);
    float w11 = wx * wy * ((vx1 && vy1) ? 1.0f : 0.0f);

    size_t r0 = (size_t)cy0 * HW;
    size_t r1 = (size_t)cy1 * HW;

#pragma unroll
    for (int c = 0; c < 3; ++c) {
        const float* base = img + ((size_t)(b * 3 + c) * HW) * HW;
        float v = base[r0 + cx0] * w00 + base[r0 + cx1] * w01 +
                  base[r1 + cx0] * w10 + base[r1 + cx1] * w11;
        out_img[(size_t)(b * 3 + c) * TEXD * TEXD + t] = v;
    }
    out_mask[(size_t)b * TEXD * TEXD + t] = maskv;
}

extern "C" void kernel_launch(void* const* d_in, const int* in_sizes, int n_in,
                              void* d_out, int out_size, void* d_ws, size_t ws_size,
                              hipStream_t stream) {
    const float* source_img = (const float*)d_in[0];
    const float* tmv        = (const float*)d_in[1];
    const float* vn         = (const float*)d_in[2];
    const float* cam        = (const float*)d_in[3];
    const int*   faces      = (const int*)d_in[4];
    const float* bc         = (const float*)d_in[5];
    const int*   xs         = (const int*)d_in[6];
    const int*   ys         = (const int*)d_in[7];

    int B = in_sizes[3] / 3;                       // 16
    int P = in_sizes[4] / 3;                       // 60000
    int V = in_sizes[1] / (3 * B);                 // 5023
    int HW = (int)(sqrt((double)(in_sizes[0] / (3 * B))) + 0.5); // 512

    int* map = (int*)d_ws;                         // TEX*TEX ints = 256 KB
    float* out_img = (float*)d_out;
    float* out_mask = out_img + (size_t)B * 3 * TEXD * TEXD;

    // map = -1 everywhere (0xFF bytes -> int -1).
    hipMemsetAsync(map, 0xFF, (size_t)TEXD * TEXD * sizeof(int), stream);

    flame_build_map_kernel<<<(P + 255) / 256, 256, 0, stream>>>(xs, ys, map, P);

    int blocks = B * ((TEXD * TEXD) / 256);        // 4096; b = blockIdx % B
    flame_fused_kernel<<<blocks, 256, 0, stream>>>(
        source_img, tmv, vn, cam, faces, bc, map, out_img, out_mask, B, V, HW);
}

// Round 3
// 151.607 us; speedup vs baseline: 1.1609x; 1.0447x over previous
//
#include <hip/hip_runtime.h>
#include <math.h>

#define TEXD 256

// 4-byte-aligned pair/triple loads: compiler may emit dwordx2/dwordx3
// (gfx950 supports unaligned global vector access); worst case it splits
// into dword loads and we're no worse than scalar.
struct alignas(4) F2 { float x, y; };
struct alignas(4) F3 { float x, y, z; };
struct alignas(4) I3 { int a, b, c; };

// Phase 1: tiny scatter — build texel -> p map (same for all batches).
__global__ void flame_build_map_kernel(const int* __restrict__ xs, // [P]
                                       const int* __restrict__ ys, // [P]
                                       int* __restrict__ map,      // [TEX*TEX], pre-set to -1
                                       int P) {
    int p = blockIdx.x * blockDim.x + threadIdx.x;
    if (p >= P) return;
    map[ys[p] * TEXD + xs[p]] = p;
}

// Phase 2: fused projection + bilinear grid_sample + visibility mask.
// One thread per (b, texel). blockIdx % B keeps each XCD (blockIdx % 8)
// on 2 batches -> 6 MB image working set per 4 MB L2.
__global__ void flame_fused_kernel(const float* __restrict__ img,   // [B,3,HW,HW]
                                   const float* __restrict__ tmv,   // [B,V,3]
                                   const float* __restrict__ vn,    // [B,V,3]
                                   const float* __restrict__ cam,   // [B,3]
                                   const int*   __restrict__ faces, // [P,3]
                                   const float* __restrict__ bc,    // [P,3]
                                   const int*   __restrict__ map,   // [TEX*TEX]
                                   float* __restrict__ out_img,     // [B,3,TEX,TEX]
                                   float* __restrict__ out_mask,    // [B,TEX,TEX]
                                   int B, int V, int HW) {
    int b = blockIdx.x % B;
    int tile = blockIdx.x / B;
    int t = tile * blockDim.x + threadIdx.x;
    if (t >= TEXD * TEXD) return;

    int p = map[t];

    float gxn = 0.0f, gyn = 0.0f;
    float maskv = 0.0f;

    if (p >= 0) {
        I3 f3 = *(const I3*)(faces + p * 3);
        F3 w3 = *(const F3*)(bc + p * 3);

        const float* tb = tmv + (size_t)b * V * 3;
        F2 v0 = *(const F2*)(tb + f3.a * 3);
        F2 v1 = *(const F2*)(tb + f3.b * 3);
        F2 v2 = *(const F2*)(tb + f3.c * 3);
        float px = v0.x * w3.x + v1.x * w3.y + v2.x * w3.z;
        float py = v0.y * w3.x + v1.y * w3.y + v2.y * w3.z;

        const float* nb = vn + (size_t)b * V * 3;
        float nz = nb[f3.a * 3 + 2] * w3.x + nb[f3.b * 3 + 2] * w3.y +
                   nb[f3.c * 3 + 2] * w3.z;

        float fo = cam[b * 3 + 0];
        float cx = cam[b * 3 + 1];
        float cy = cam[b * 3 + 2];
        gxn = fo * (px + cx);
        gyn = -(fo * (py + cy));
        maskv = (nz < 0.0f) ? 1.0f : 0.0f;
    }

    // --- bilinear grid_sample, zero padding, align_corners=False ---
    float half = 0.5f * (float)HW;
    float gx = (gxn + 1.0f) * half - 0.5f;
    float gy = (gyn + 1.0f) * half - 0.5f;

    float x0f = floorf(gx);
    float y0f = floorf(gy);
    float wx = gx - x0f;
    float wy = gy - y0f;
    int x0 = (int)x0f;
    int y0 = (int)y0f;
    int x1 = x0 + 1;
    int y1 = y0 + 1;

    bool vx0 = (x0 >= 0) && (x0 <= HW - 1);
    bool vx1 = (x1 >= 0) && (x1 <= HW - 1);
    bool vy0 = (y0 >= 0) && (y0 <= HW - 1);
    bool vy1 = (y1 >= 0) && (y1 <= HW - 1);

    float w00 = (1.0f - wx) * (1.0f - wy) * ((vx0 && vy0) ? 1.0f : 0.0f);
    float w01 = wx * (1.0f - wy) * ((vx1 && vy0) ? 1.0f : 0.0f);
    float w10 = (1.0f - wx) * wy * ((vx0 && vy1) ? 1.0f : 0.0f);
    float w11 = wx * wy * ((vx1 && vy1) ? 1.0f : 0.0f);

    // Pair-load base column, clamped so [xb, xb+1] is always in range.
    int xb = min(max(x0, 0), HW - 2);
    bool lo = (x0 == xb);      // .x element corresponds to x0-corner?
    float wl0 = lo ? w00 : w01;  // weight applied to .x of row y0
    float wh0 = lo ? w01 : w00;  // weight applied to .y of row y0
    float wl1 = lo ? w10 : w11;  // weight applied to .x of row y1
    float wh1 = lo ? w11 : w10;  // weight applied to .y of row y1

    int cy0 = min(max(y0, 0), HW - 1);
    int cy1 = min(max(y1, 0), HW - 1);
    size_t r0 = (size_t)cy0 * HW + xb;
    size_t r1 = (size_t)cy1 * HW + xb;

#pragma unroll
    for (int c = 0; c < 3; ++c) {
        const float* base = img + ((size_t)(b * 3 + c) * HW) * HW;
        F2 a = *(const F2*)(base + r0);
        F2 d = *(const F2*)(base + r1);
        float v = a.x * wl0 + a.y * wh0 + d.x * wl1 + d.y * wh1;
        out_img[(size_t)(b * 3 + c) * TEXD * TEXD + t] = v;
    }
    out_mask[(size_t)b * TEXD * TEXD + t] = maskv;
}

extern "C" void kernel_launch(void* const* d_in, const int* in_sizes, int n_in,
                              void* d_out, int out_size, void* d_ws, size_t ws_size,
                              hipStream_t stream) {
    const float* source_img = (const float*)d_in[0];
    const float* tmv        = (const float*)d_in[1];
    const float* vn         = (const float*)d_in[2];
    const float* cam        = (const float*)d_in[3];
    const int*   faces      = (const int*)d_in[4];
    const float* bc         = (const float*)d_in[5];
    const int*   xs         = (const int*)d_in[6];
    const int*   ys         = (const int*)d_in[7];

    int B = in_sizes[3] / 3;                       // 16
    int P = in_sizes[4] / 3;                       // 60000
    int V = in_sizes[1] / (3 * B);                 // 5023
    int HW = (int)(sqrt((double)(in_sizes[0] / (3 * B))) + 0.5); // 512

    int* map = (int*)d_ws;                         // TEX*TEX ints = 256 KB
    float* out_img = (float*)d_out;
    float* out_mask = out_img + (size_t)B * 3 * TEXD * TEXD;

    // map = -1 everywhere (0xFF bytes -> int -1).
    hipMemsetAsync(map, 0xFF, (size_t)TEXD * TEXD * sizeof(int), stream);

    flame_build_map_kernel<<<(P + 255) / 256, 256, 0, stream>>>(xs, ys, map, P);

    int blocks = B * ((TEXD * TEXD) / 256);        // 4096; b = blockIdx % B
    flame_fused_kernel<<<blocks, 256, 0, stream>>>(
        source_img, tmv, vn, cam, faces, bc, map, out_img, out_mask, B, V, HW);
}

// Round 4
// 142.009 us; speedup vs baseline: 1.2394x; 1.0676x over previous
//
#include <hip/hip_runtime.h>
#include <math.h>

#define TEXD 256

struct alignas(4) F3 { float x, y, z; };
struct alignas(4) I3 { int a, b, c; };

// Phase 0a: texel -> p map (identical for all batches).
__global__ void flame_build_map_kernel(const int* __restrict__ xs, // [P]
                                       const int* __restrict__ ys, // [P]
                                       int* __restrict__ map,      // [TEX*TEX], pre-set -1
                                       int P) {
    int p = blockIdx.x * blockDim.x + threadIdx.x;
    if (p >= P) return;
    map[ys[p] * TEXD + xs[p]] = p;
}

// Phase 0b: packed per-(b,v) vertex record: (x, y, nz, 0) as aligned float4
// so the per-texel vertex gather is one dwordx4 (never line-splitting).
__global__ void flame_pack_verts_kernel(const float* __restrict__ tmv, // [B,V,3]
                                        const float* __restrict__ vn,  // [B,V,3]
                                        float4* __restrict__ pv,       // [B*V]
                                        int n) {
    int i = blockIdx.x * blockDim.x + threadIdx.x;
    if (i >= n) return;
    pv[i] = make_float4(tmv[i * 3 + 0], tmv[i * 3 + 1], vn[i * 3 + 2], 0.0f);
}

// Bilinear grid_sample (zero padding, align_corners=False), 3 channels.
__device__ __forceinline__ void sample3(const float* __restrict__ img, int bc_,
                                        int HW, float gxn, float gyn,
                                        float out[3]) {
    float half = 0.5f * (float)HW;
    float gx = (gxn + 1.0f) * half - 0.5f;
    float gy = (gyn + 1.0f) * half - 0.5f;

    float x0f = floorf(gx);
    float y0f = floorf(gy);
    float wx = gx - x0f;
    float wy = gy - y0f;
    int x0 = (int)x0f;
    int y0 = (int)y0f;
    int x1 = x0 + 1;
    int y1 = y0 + 1;

    bool vx0 = (x0 >= 0) && (x0 <= HW - 1);
    bool vx1 = (x1 >= 0) && (x1 <= HW - 1);
    bool vy0 = (y0 >= 0) && (y0 <= HW - 1);
    bool vy1 = (y1 >= 0) && (y1 <= HW - 1);

    float w00 = (1.0f - wx) * (1.0f - wy) * ((vx0 && vy0) ? 1.0f : 0.0f);
    float w01 = wx * (1.0f - wy) * ((vx1 && vy0) ? 1.0f : 0.0f);
    float w10 = (1.0f - wx) * wy * ((vx0 && vy1) ? 1.0f : 0.0f);
    float w11 = wx * wy * ((vx1 && vy1) ? 1.0f : 0.0f);

    // Pair-load base column clamped so [xb, xb+1] is in range; swap weights
    // if the clamp shifted the pair.
    int xb = min(max(x0, 0), HW - 2);
    bool lo = (x0 == xb);
    float wl0 = lo ? w00 : w01;
    float wh0 = lo ? w01 : w00;
    float wl1 = lo ? w10 : w11;
    float wh1 = lo ? w11 : w10;

    int cy0 = min(max(y0, 0), HW - 1);
    int cy1 = min(max(y1, 0), HW - 1);
    size_t r0 = (size_t)cy0 * HW + xb;
    size_t r1 = (size_t)cy1 * HW + xb;

    const float* base = img + (size_t)bc_ * HW * HW * 3;
#pragma unroll
    for (int c = 0; c < 3; ++c) {
        const float* pl = base + (size_t)c * HW * HW;
        F3 dummy; (void)dummy;
        float a0 = pl[r0], a1 = pl[r0 + 1];
        float d0 = pl[r1], d1 = pl[r1 + 1];
        out[c] = a0 * wl0 + a1 * wh0 + d0 * wl1 + d1 * wh1;
    }
}

// Phase 1: fused projection + grid_sample + mask for TWO batches per thread
// (b0 and b0 + B/2). The pair shares map/faces/bc loads and doubles the
// number of independent latency chains per wave. blockIdx % (B/2) keeps an
// XCD (blockIdx % 8) on one batch pair -> 6 MB image working set per L2.
__global__ void flame_fused2_kernel(const float* __restrict__ img,   // [B,3,HW,HW]
                                    const float4* __restrict__ pv,   // [B*V]
                                    const float* __restrict__ cam,   // [B,3]
                                    const int*   __restrict__ faces, // [P,3]
                                    const float* __restrict__ bcw,   // [P,3]
                                    const int*   __restrict__ map,   // [TEX*TEX]
                                    float* __restrict__ out_img,     // [B,3,TEX,TEX]
                                    float* __restrict__ out_mask,    // [B,TEX,TEX]
                                    int B, int V, int HW) {
    int npair = B >> 1;
    int pair = blockIdx.x % npair;
    int tile = blockIdx.x / npair;
    int t = tile * blockDim.x + threadIdx.x;
    if (t >= TEXD * TEXD) return;

    int b0 = pair;
    int b1 = pair + npair;

    int p = map[t];

    float gxn0 = 0.0f, gyn0 = 0.0f, m0 = 0.0f;
    float gxn1 = 0.0f, gyn1 = 0.0f, m1 = 0.0f;

    if (p >= 0) {
        I3 f3 = *(const I3*)(faces + p * 3);
        F3 w3 = *(const F3*)(bcw + p * 3);

        const float4* pv0 = pv + (size_t)b0 * V;
        const float4* pv1 = pv + (size_t)b1 * V;
        // Issue all six vertex gathers before consuming (independent chains).
        float4 a0 = pv0[f3.a];
        float4 a1 = pv0[f3.b];
        float4 a2 = pv0[f3.c];
        float4 c0 = pv1[f3.a];
        float4 c1 = pv1[f3.b];
        float4 c2 = pv1[f3.c];

        float px0 = a0.x * w3.x + a1.x * w3.y + a2.x * w3.z;
        float py0 = a0.y * w3.x + a1.y * w3.y + a2.y * w3.z;
        float nz0 = a0.z * w3.x + a1.z * w3.y + a2.z * w3.z;
        float px1 = c0.x * w3.x + c1.x * w3.y + c2.x * w3.z;
        float py1 = c0.y * w3.x + c1.y * w3.y + c2.y * w3.z;
        float nz1 = c0.z * w3.x + c1.z * w3.y + c2.z * w3.z;

        float f0 = cam[b0 * 3 + 0], cx0 = cam[b0 * 3 + 1], cy0 = cam[b0 * 3 + 2];
        float f1 = cam[b1 * 3 + 0], cx1 = cam[b1 * 3 + 1], cy1 = cam[b1 * 3 + 2];
        gxn0 = f0 * (px0 + cx0);
        gyn0 = -(f0 * (py0 + cy0));
        gxn1 = f1 * (px1 + cx1);
        gyn1 = -(f1 * (py1 + cy1));
        m0 = (nz0 < 0.0f) ? 1.0f : 0.0f;
        m1 = (nz1 < 0.0f) ? 1.0f : 0.0f;
    }

    float o0[3], o1[3];
    sample3(img, b0, HW, gxn0, gyn0, o0);
    sample3(img, b1, HW, gxn1, gyn1, o1);

    size_t plane = (size_t)TEXD * TEXD;
#pragma unroll
    for (int c = 0; c < 3; ++c) {
        __builtin_nontemporal_store(o0[c], out_img + ((size_t)(b0 * 3 + c)) * plane + t);
        __builtin_nontemporal_store(o1[c], out_img + ((size_t)(b1 * 3 + c)) * plane + t);
    }
    __builtin_nontemporal_store(m0, out_mask + (size_t)b0 * plane + t);
    __builtin_nontemporal_store(m1, out_mask + (size_t)b1 * plane + t);
}

extern "C" void kernel_launch(void* const* d_in, const int* in_sizes, int n_in,
                              void* d_out, int out_size, void* d_ws, size_t ws_size,
                              hipStream_t stream) {
    const float* source_img = (const float*)d_in[0];
    const float* tmv        = (const float*)d_in[1];
    const float* vn         = (const float*)d_in[2];
    const float* cam        = (const float*)d_in[3];
    const int*   faces      = (const int*)d_in[4];
    const float* bcw        = (const float*)d_in[5];
    const int*   xs         = (const int*)d_in[6];
    const int*   ys         = (const int*)d_in[7];

    int B = in_sizes[3] / 3;                       // 16
    int P = in_sizes[4] / 3;                       // 60000
    int V = in_sizes[1] / (3 * B);                 // 5023
    int HW = (int)(sqrt((double)(in_sizes[0] / (3 * B))) + 0.5); // 512

    int* map = (int*)d_ws;                         // 256 KB
    float4* pv = (float4*)((char*)d_ws + (size_t)TEXD * TEXD * sizeof(int));

    float* out_img = (float*)d_out;
    float* out_mask = out_img + (size_t)B * 3 * TEXD * TEXD;

    hipMemsetAsync(map, 0xFF, (size_t)TEXD * TEXD * sizeof(int), stream);

    flame_build_map_kernel<<<(P + 255) / 256, 256, 0, stream>>>(xs, ys, map, P);

    int nv = B * V;
    flame_pack_verts_kernel<<<(nv + 255) / 256, 256, 0, stream>>>(tmv, vn, pv, nv);

    int npair = B / 2;                             // 8
    int blocks = npair * ((TEXD * TEXD) / 256);    // 2048
    flame_fused2_kernel<<<blocks, 256, 0, stream>>>(
        source_img, pv, cam, faces, bcw, map, out_img, out_mask, B, V, HW);
}